// Round 6
// baseline (4064.982 us; speedup 1.0000x reference)
//
#include <hip/hip_runtime.h>

// ---------------------------------------------------------------------------
// LSTM_small2 R6: deep-K fused cell.
// lstm_cell2: BM=96 x BN=192 (48 hidden x 4 gates, gate-interleaved c=h'*4+g),
// BK=128 (24 steps: 12 X + 12 H). A direct-to-reg; B via global_load_lds into
// dbuf LDS (row=256B, slot^=row&15 swizzle). Grid 256 exact (8 bm x 32 strips).
// Gates gathered across 4-lane groups via shfl_xor; c fp32, h bf16.
// ---------------------------------------------------------------------------

typedef unsigned short u16;
typedef unsigned int   u32;
typedef __bf16 bf16x8 __attribute__((ext_vector_type(8)));
typedef short  short8 __attribute__((ext_vector_type(8)));
typedef float  f32x4  __attribute__((ext_vector_type(4)));

__device__ __forceinline__ u16 f2bf(float f) {
  u32 u = __float_as_uint(f);
  u32 r = u + 0x7FFFu + ((u >> 16) & 1u);   // RNE
  return (u16)(r >> 16);
}

__device__ __forceinline__ f32x4 mfma16(short8 a, short8 b, f32x4 c) {
  return __builtin_amdgcn_mfma_f32_16x16x32_bf16(
      __builtin_bit_cast(bf16x8, a), __builtin_bit_cast(bf16x8, b), c, 0, 0, 0);
}

__device__ __forceinline__ void gload16(const u16* g, u16* l) {
  __builtin_amdgcn_global_load_lds(
      (const __attribute__((address_space(1))) u32*)g,
      (__attribute__((address_space(3))) u32*)l, 16, 0, 0);
}

// ---------------------------------------------------------------------------
// Fused LSTM cell v2. X,H: [768][1536] bf16. Wih/Whh packed: row c=h*4+g,
// i.e. Wpk[(h*4+g)][k] = W[g*1536+h][k], bf16 [6144][1536]. bcomb[c]=bi+bh.
// Block: rows bm*96..+96, G-cols strip*192..+192 (hidden strip*48..+48).
// 4 waves; wave w owns n-frags {3w,3w+1,3w+2} x all 6 m-frags.
// ---------------------------------------------------------------------------
__global__ __launch_bounds__(256) void lstm_cell2(
    const u16* __restrict__ X, const u16* __restrict__ H,
    const u16* __restrict__ Wih, const u16* __restrict__ Whh,
    const float* __restrict__ bcomb,
    float* __restrict__ c, u16* __restrict__ hout, u16* __restrict__ h2)
{
  __shared__ __align__(16) u16 smem[2 * 24576];    // B dbuf: [2][192 rows][128 u16]
  const int tid  = threadIdx.x;
  const int wid  = ((blockIdx.x & 7) << 5) + (blockIdx.x >> 3);  // XCD-chunked
  const int strip = wid >> 3;                  // [0,32): 48 hidden / 192 G-cols
  const int bm    = wid & 7;                   // [0,8): 96 rows
  const int lane = tid & 63, wave = tid >> 6;
  const int r16  = lane & 15, kg = lane >> 4;

  f32x4 acc[6][3];
#pragma unroll
  for (int mi = 0; mi < 6; ++mi)
#pragma unroll
    for (int nf = 0; nf < 3; ++nf) acc[mi][nf] = (f32x4)0.0f;

  // staging geometry: 12 calls/thread cover 192 rows x 256B
  const int srow4 = (wave << 2) + kg;          // row offset within 16-row group
  const int s_src = r16 ^ (srow4 & 15);        // inverse-swizzled source slot

  auto stageB = [&](int i, int buf) {
    const u16* W = (i < 12) ? Wih : Whh;
    const int k0 = ((i < 12) ? i : (i - 12)) << 7;
    const u16* src0 = W + (size_t)(strip * 192) * 1536 + k0 + s_src * 8;
    u16* dst0 = smem + buf * 24576 + wave * 512 + 0;   // + t*2048
#pragma unroll
    for (int t = 0; t < 12; ++t) {
      const int row = t * 16 + srow4;
      gload16(src0 + (size_t)row * 1536, dst0 + t * 2048);
    }
  };

  // A row bases (lane-private): rows bm*96 + mi*16 + r16, k-chunk kg*8
  size_t arow[6];
#pragma unroll
  for (int mi = 0; mi < 6; ++mi)
    arow[mi] = (size_t)(bm * 96 + mi * 16 + r16) * 1536 + kg * 8;

  stageB(0, 0);
  __syncthreads();
  int cur = 0;
  for (int i = 0; i < 24; ++i) {
    if (i + 1 < 24) stageB(i + 1, cur ^ 1);
    const u16* Aseg = (i < 12) ? X : H;
    const int koff = ((i < 12) ? i : (i - 12)) << 7;
    // A frags for this step: 6 m x 4 kf (issued early; compiler pipelines)
    short8 af[6][4];
#pragma unroll
    for (int mi = 0; mi < 6; ++mi)
#pragma unroll
      for (int kf = 0; kf < 4; ++kf)
        af[mi][kf] = *(const short8*)(Aseg + arow[mi] + koff + kf * 32);
    const u16* baseB = smem + cur * 24576;
#pragma unroll
    for (int kf = 0; kf < 4; ++kf) {
      short8 bfr[3];
#pragma unroll
      for (int j = 0; j < 3; ++j) {
        const int nf = wave * 3 + j;
        const int row = nf * 16 + r16;
        const int slot = (kf * 4 + kg) ^ r16;        // swizzled read slot
        bfr[j] = *(const short8*)(baseB + row * 128 + slot * 8);
      }
#pragma unroll
      for (int mi = 0; mi < 6; ++mi)
#pragma unroll
        for (int j = 0; j < 3; ++j)
          acc[mi][j] = mfma16(af[mi][kf], bfr[j], acc[mi][j]);
    }
    __syncthreads();
    cur ^= 1;
  }

  // ---- fused gate epilogue (gate-interleaved: lane group of 4 = i,f,g,o) ----
  const int gl = lane & 3;
  const int hq = r16 >> 2;                      // hidden sub-index within frag
#pragma unroll
  for (int j3 = 0; j3 < 3; ++j3) {
    const int nf = wave * 3 + j3;
    const float bv = bcomb[strip * 192 + nf * 16 + r16];
    const int hglob = strip * 48 + nf * 4 + hq;
#pragma unroll
    for (int mi = 0; mi < 6; ++mi) {
#pragma unroll
      for (int j = 0; j < 4; ++j) {
        const float v0 = acc[mi][j3][j] + bv;
        const float v1 = __shfl_xor(v0, 1);
        const float v2 = __shfl_xor(v0, 2);
        const float v3 = __shfl_xor(v0, 3);
        // gate q's value = v_{gl^q}
        const float ig = (gl == 0) ? v0 : (gl == 1) ? v1 : (gl == 2) ? v2 : v3;
        const float fg = ((gl ^ 1) == 0) ? v0 : ((gl ^ 1) == 1) ? v1 : ((gl ^ 1) == 2) ? v2 : v3;
        const float gz = ((gl ^ 2) == 0) ? v0 : ((gl ^ 2) == 1) ? v1 : ((gl ^ 2) == 2) ? v2 : v3;
        const float og = ((gl ^ 3) == 0) ? v0 : ((gl ^ 3) == 1) ? v1 : ((gl ^ 3) == 2) ? v2 : v3;
        if (gl == 0) {
          const int row = bm * 96 + mi * 16 + kg * 4 + j;
          const size_t cij = (size_t)row * 1536 + hglob;
          const float si = 1.0f / (1.0f + expf(-ig));
          const float sf = 1.0f / (1.0f + expf(-fg));
          const float so = 1.0f / (1.0f + expf(-og));
          const float cnew = sf * c[cij] + si * tanhf(gz);
          c[cij] = cnew;
          const u16 hv = f2bf(so * tanhf(cnew));
          hout[cij] = hv;
          if (h2) h2[cij] = hv;
        }
      }
    }
  }
}

// ---------------------------------------------------------------------------
// B^T GEMM (attention projections): C = A1·B1^T (+bias). 128x128 tile, BK=32.
// ---------------------------------------------------------------------------
template <int OUT_BF16, int HAS_BIAS>
__global__ __launch_bounds__(256, 2) void gemm_bt(
    const u16* __restrict__ A1, const u16* __restrict__ B1, int K1,
    const float* __restrict__ bias, void* __restrict__ Cout, int N)
{
  __shared__ __align__(16) u16 smem[16384];
  const int tid  = threadIdx.x;
  const int bn   = blockIdx.x * 128;
  const int bm   = blockIdx.y * 128;
  const int lane = tid & 63, wave = tid >> 6;
  const int wm   = (wave >> 1) * 64, wn = (wave & 1) * 64;
  const int r16  = lane & 15, kg = lane >> 4;
  const int srow = lane >> 2, sslot = lane & 3;

  f32x4 acc[4][4];
#pragma unroll
  for (int i = 0; i < 4; ++i)
#pragma unroll
    for (int j = 0; j < 4; ++j) acc[i][j] = (f32x4)0.0f;

  const int nt = K1 >> 5;
  auto stage = [&](int i, int buf) {
    const int k0 = i << 5;
#pragma unroll
    for (int cc2 = 0; cc2 < 2; ++cc2) {
      const int call = wave * 2 + cc2;
      const int row  = call * 16 + srow;
      const int slog = sslot ^ ((row >> 1) & 3);
      gload16(A1 + (size_t)(bm + row) * K1 + k0 + slog * 8, smem + buf * 4096 + call * 512);
      gload16(B1 + (size_t)(bn + row) * K1 + k0 + slog * 8, smem + 8192 + buf * 4096 + call * 512);
    }
  };

  stage(0, 0);
  __syncthreads();
  int cur = 0;
  for (int i = 0; i < nt; ++i) {
    if (i + 1 < nt) stage(i + 1, cur ^ 1);
    const u16* baseA = smem + cur * 4096;
    const u16* baseB = smem + 8192 + cur * 4096;
    short8 af[4], bfr[4];
#pragma unroll
    for (int mi = 0; mi < 4; ++mi) {
      const int row = wm + mi * 16 + r16;
      af[mi] = *(const short8*)(baseA + row * 32 + ((kg ^ ((row >> 1) & 3)) << 3));
    }
#pragma unroll
    for (int ni = 0; ni < 4; ++ni) {
      const int row = wn + ni * 16 + r16;
      bfr[ni] = *(const short8*)(baseB + row * 32 + ((kg ^ ((row >> 1) & 3)) << 3));
    }
#pragma unroll
    for (int mi = 0; mi < 4; ++mi)
#pragma unroll
      for (int ni = 0; ni < 4; ++ni)
        acc[mi][ni] = mfma16(af[mi], bfr[ni], acc[mi][ni]);
    __syncthreads();
    cur ^= 1;
  }

  const size_t Ns = (size_t)N;
#pragma unroll
  for (int ni = 0; ni < 4; ++ni) {
    const int col = bn + wn + ni * 16 + r16;
    const float bvv = HAS_BIAS ? bias[col] : 0.0f;
#pragma unroll
    for (int mi = 0; mi < 4; ++mi) {
      const int row0 = bm + wm + mi * 16 + kg * 4;
      f32x4 v = acc[mi][ni];
#pragma unroll
      for (int j = 0; j < 4; ++j) {
        const float val = v[j] + bvv;
        const size_t idx = (size_t)(row0 + j) * Ns + col;
        if (OUT_BF16) ((u16*)Cout)[idx] = f2bf(val);
        else          ((float*)Cout)[idx] = val;
      }
    }
  }
}

// ---------------------------------------------------------------------------
// Attention: one block per (nb, b); wave = head. T=12 padded to 16, DK=128.
// ---------------------------------------------------------------------------
__global__ __launch_bounds__(256) void attn_kernel(const u16* __restrict__ P, u16* __restrict__ O)
{
  __shared__ __align__(16) u16 sQ[12 * 520];
  __shared__ __align__(16) u16 sK[12 * 520];
  __shared__ __align__(16) u16 sVT[512 * 24];
  __shared__ __align__(16) u16 sS[4 * 16 * 16];
  const int tid = threadIdx.x;
  const int nb = blockIdx.x >> 8;
  const int b  = blockIdx.x & 255;
  const int qb = (nb == 1) ? 0 : 1;   // q perm [1,0,1]
  const int kb = (nb == 2) ? 0 : 2;   // k perm [2,2,0]
  const size_t rq = ((size_t)qb * 256 + b) * 12;
  const size_t rk = ((size_t)kb * 256 + b) * 12;
  const size_t rv = ((size_t)nb * 256 + b) * 12;

  for (int e4 = tid; e4 < 1536; e4 += 256) {
    const int t  = e4 >> 7;
    const int cc = (e4 & 127) * 4;
    uint2 qv = *(const uint2*)(P + (rq + t) * 1536 + cc);
    *(uint2*)(sQ + t * 520 + cc) = qv;
    uint2 kv = *(const uint2*)(P + (rk + t) * 1536 + 512 + cc);
    *(uint2*)(sK + t * 520 + cc) = kv;
    uint2 vv = *(const uint2*)(P + (rv + t) * 1536 + 1024 + cc);
    sVT[(cc + 0) * 24 + t] = (u16)(vv.x & 0xffff);
    sVT[(cc + 1) * 24 + t] = (u16)(vv.x >> 16);
    sVT[(cc + 2) * 24 + t] = (u16)(vv.y & 0xffff);
    sVT[(cc + 3) * 24 + t] = (u16)(vv.y >> 16);
  }
  for (int i = tid; i < 2048; i += 256) sVT[(i >> 2) * 24 + 12 + (i & 3)] = 0;
  __syncthreads();

  const int lane = tid & 63, h = tid >> 6;
  const int r16 = lane & 15, kg = lane >> 4;
  const int hcol = h * 128;

  f32x4 sc = (f32x4)0.0f;
#pragma unroll
  for (int ks = 0; ks < 4; ++ks) {
    short8 aq  = (r16 < 12) ? *(const short8*)(sQ + r16 * 520 + hcol + ks * 32 + kg * 8) : (short8)0;
    short8 bk2 = (r16 < 12) ? *(const short8*)(sK + r16 * 520 + hcol + ks * 32 + kg * 8) : (short8)0;
    sc = mfma16(aq, bk2, sc);   // scores[q=(kg*4+j)][tok=r16]
  }
  const float scale = 0.08838834764831845f;  // 1/sqrt(128)
#pragma unroll
  for (int j = 0; j < 4; ++j) {
    float v = (r16 < 12) ? sc[j] * scale : -1e30f;
    float m = v;
#pragma unroll
    for (int d = 1; d < 16; d <<= 1) m = fmaxf(m, __shfl_xor(m, d));
    float e = expf(v - m);
    float s = e;
#pragma unroll
    for (int d = 1; d < 16; d <<= 1) s += __shfl_xor(s, d);
    sS[h * 256 + (kg * 4 + j) * 16 + r16] = f2bf(e / s);
  }
  __syncthreads();
  short8 av = (kg < 2) ? *(const short8*)(sS + h * 256 + r16 * 16 + kg * 8) : (short8)0;
#pragma unroll
  for (int dt = 0; dt < 8; ++dt) {
    short8 bv2 = (kg < 2) ? *(const short8*)(sVT + (hcol + dt * 16 + r16) * 24 + kg * 8) : (short8)0;
    f32x4 ov = mfma16(av, bv2, (f32x4)0.0f);  // out[q=(kg*4+j)][d=dt*16+r16]
    if (kg < 3) {
#pragma unroll
      for (int j = 0; j < 4; ++j) {
        const int q = kg * 4 + j;
        O[(rv + q) * 512 + hcol + dt * 16 + r16] = f2bf(ov[j]);
      }
    }
  }
}

// ---------------------------------------------------------------------------
// LayerNorm over C=768 per row; writes feature and the [:,1:5,1:5,:] crop.
// ---------------------------------------------------------------------------
__global__ __launch_bounds__(256) void layernorm_kernel(
    const float* __restrict__ feat, const float* __restrict__ gam,
    const float* __restrict__ bet, float* __restrict__ out)
{
  const int row = blockIdx.x;
  const int b = row / 36, hidx = row - b * 36;
  const int nb = hidx / 12, t = hidx - nb * 12;
  const float* src = feat + ((size_t)nb * 3072 + b * 12 + t) * 768;
  const int tid = threadIdx.x;
  float v0 = src[tid], v1 = src[tid + 256], v2 = src[tid + 512];
  float s = v0 + v1 + v2, sq = v0 * v0 + v1 * v1 + v2 * v2;
#pragma unroll
  for (int d = 1; d < 64; d <<= 1) { s += __shfl_xor(s, d); sq += __shfl_xor(sq, d); }
  __shared__ float ps[4], pq[4];
  if ((tid & 63) == 0) { ps[tid >> 6] = s; pq[tid >> 6] = sq; }
  __syncthreads();
  s  = ps[0] + ps[1] + ps[2] + ps[3];
  sq = pq[0] + pq[1] + pq[2] + pq[3];
  const float mean = s * (1.0f / 768.0f);
  const float var  = sq * (1.0f / 768.0f) - mean * mean;
  const float rstd = rsqrtf(var + 1e-5f);
  float* dst = out + (size_t)row * 768;
  const int hh = hidx / 6, wp = hidx - hh * 6;
  float* dst2 = nullptr;
  if (hh >= 1 && hh < 5 && wp >= 1 && wp < 5)
    dst2 = out + 7077888 + ((size_t)b * 16 + (hh - 1) * 4 + (wp - 1)) * 768;
#pragma unroll
  for (int i = 0; i < 3; ++i) {
    const int cix = tid + i * 256;
    const float vv = (i == 0) ? v0 : (i == 1 ? v1 : v2);
    const float o = (vv - mean) * rstd * gam[cix] + bet[cix];
    dst[cix] = o;
    if (dst2) dst2[cix] = o;
  }
}

// --------------------------- small prep kernels ----------------------------
// LSTM weights: fp32 [2][6144][1536] -> bf16 gate-interleaved rows:
// dst[L][h*4+g][k] = src[L][g*1536+h][k]
__global__ __launch_bounds__(256) void pack_lstm_w(const float* __restrict__ src,
                                                   u16* __restrict__ dst)
{
  const int i4 = blockIdx.x * 256 + threadIdx.x;   // < 4718592
  if (i4 >= 4718592) return;
  const int e = i4 * 4;
  const int k = e % 1536;
  const int r = (e / 1536) % 6144;
  const int L = e / (6144 * 1536);
  const int g = r & 3, hh = r >> 2;
  const float* s = src + ((size_t)L * 6144 + g * 1536 + hh) * 1536 + k;
  float4 v = *(const float4*)s;
  uint2 pk;
  pk.x = (u32)f2bf(v.x) | ((u32)f2bf(v.y) << 16);
  pk.y = (u32)f2bf(v.z) | ((u32)f2bf(v.w) << 16);
  ((uint2*)dst)[i4] = pk;
}

// bcomb[L][h*4+g] = bi[L][g*1536+h] + bh[L][g*1536+h]  (2 layers per call)
__global__ __launch_bounds__(256) void pack_bias_lstm(const float* __restrict__ bi,
    const float* __restrict__ bh, float* __restrict__ dst)
{
  const int i = blockIdx.x * 256 + threadIdx.x;    // < 12288
  if (i >= 12288) return;
  const int c = i % 6144, L = i / 6144;
  const int g = c & 3, hh = c >> 2;
  dst[i] = bi[L * 6144 + g * 1536 + hh] + bh[L * 6144 + g * 1536 + hh];
}

__global__ __launch_bounds__(256) void pack_qkvT(const float* __restrict__ Wq,
    const float* __restrict__ Wk, const float* __restrict__ Wv, u16* __restrict__ dst)
{
  const int idx = blockIdx.x * 256 + threadIdx.x;   // 1536*768
  if (idx >= 1536 * 768) return;
  const int d = idx / 768, c = idx - d * 768;
  float v;
  if (d < 512)       v = Wq[(size_t)c * 512 + d];
  else if (d < 1024) v = Wk[(size_t)c * 512 + d - 512];
  else               v = Wv[(size_t)c * 512 + d - 1024];
  dst[idx] = f2bf(v);
}

__global__ __launch_bounds__(256) void pack_bias(const float* __restrict__ bq,
    const float* __restrict__ bk, const float* __restrict__ bv, float* __restrict__ dst)
{
  const int i = blockIdx.x * 256 + threadIdx.x;
  if (i < 512)       dst[i] = bq[i];
  else if (i < 1024) dst[i] = bk[i - 512];
  else if (i < 1536) dst[i] = bv[i - 1024];
}

__global__ __launch_bounds__(256) void pack_WoT(const float* __restrict__ Wo, u16* __restrict__ dst)
{
  const int idx = blockIdx.x * 256 + threadIdx.x;   // 768*512
  if (idx >= 768 * 512) return;
  const int n = idx / 512, k = idx - n * 512;
  dst[idx] = f2bf(Wo[(size_t)k * 768 + n]);
}

// Xe[s][r][k] = x[b][(nb*2+r2)*6 + (5-s)][c], r=nb*256+b, k=r2*768+c  (bf16)
__global__ __launch_bounds__(256) void build_Xe(const float* __restrict__ x, u16* __restrict__ Xe)
{
  const int i4 = blockIdx.x * 256 + threadIdx.x;   // < 1769472
  if (i4 >= 1769472) return;
  const int e = i4 * 4;
  const int c = e % 768;
  const int r2 = (e / 768) & 1;
  const int r = (e / 1536) % 768;
  const int s = e / 1179648;
  const int nb = r >> 8, bb = r & 255;
  const int w = 5 - s;
  const float* src = x + ((size_t)bb * 36 + (nb * 2 + r2) * 6 + w) * 768 + c;
  float4 v = *(const float4*)src;
  uint2 pk;
  pk.x = (u32)f2bf(v.x) | ((u32)f2bf(v.y) << 16);
  pk.y = (u32)f2bf(v.z) | ((u32)f2bf(v.w) << 16);
  ((uint2*)Xe)[i4] = pk;
}

// xt[nb][b][t][c] = dec_ys[s][nb*256+b][r2*768+c], t = r2*6+s  (bf16 copy)
__global__ __launch_bounds__(256) void build_xt(const u16* __restrict__ decys, u16* __restrict__ xt)
{
  const int i4 = blockIdx.x * 256 + threadIdx.x;   // < 1769472
  if (i4 >= 1769472) return;
  const int e = i4 * 4;
  const int c = e % 768;
  const int t = (e / 768) % 12;
  const int b = (e / 9216) % 256;
  const int nb = e / 2359296;
  const int r2 = t / 6, s = t - r2 * 6;
  const u16* src = decys + ((size_t)s * 768 + nb * 256 + b) * 1536 + r2 * 768 + c;
  ((uint2*)xt)[i4] = *(const uint2*)src;
}

// ---------------------------------------------------------------------------
extern "C" void kernel_launch(void* const* d_in, const int* in_sizes, int n_in,
                              void* d_out, int out_size, void* d_ws, size_t ws_size,
                              hipStream_t stream)
{
  const float* x    = (const float*)d_in[0];
  const float* eWih = (const float*)d_in[1];
  const float* eWhh = (const float*)d_in[2];
  const float* ebih = (const float*)d_in[3];
  const float* ebhh = (const float*)d_in[4];
  const float* dWih = (const float*)d_in[5];
  const float* dWhh = (const float*)d_in[6];
  const float* dbih = (const float*)d_in[7];
  const float* dbhh = (const float*)d_in[8];
  const float* Wq = (const float*)d_in[9];
  const float* bq = (const float*)d_in[10];
  const float* Wk = (const float*)d_in[11];
  const float* bk = (const float*)d_in[12];
  const float* Wv = (const float*)d_in[13];
  const float* bv = (const float*)d_in[14];
  const float* Wo = (const float*)d_in[15];
  const float* bo = (const float*)d_in[16];
  const float* lng = (const float*)d_in[17];
  const float* lnb = (const float*)d_in[18];

  char* ws = (char*)d_ws;
  // region0: packed bf16 weights (4 x 37,748,736 B), aliased post-decoder by
  // the attention-phase temporaries.
  const size_t WBYTES = 37748736;
  u16* Weih = (u16*)(ws);
  u16* Wehh = (u16*)(ws + WBYTES);
  u16* Wdih = (u16*)(ws + 2 * WBYTES);
  u16* Wdhh = (u16*)(ws + 3 * WBYTES);
  u16*   xtb   = (u16*)(ws);
  u16*   Pqkv  = (u16*)(ws + 14155776);
  u16*   Obuf  = (u16*)(ws + 14155776 + 28311552);
  float* feato = (float*)(ws + 14155776 + 28311552 + 9437184);
  size_t off = 4 * WBYTES;
  auto take = [&](size_t bytes) -> char* {
    char* p = ws + off;
    off = (off + bytes + 255) & ~(size_t)255;
    return p;
  };
  float* bcE  = (float*)take(2 * 6144 * 4);
  float* bcD  = (float*)take(2 * 6144 * 4);
  u16* Wqkv  = (u16*)take((size_t)1536 * 768 * 2);
  float* bqkv = (float*)take(1536 * 4);
  u16* WoT   = (u16*)take((size_t)768 * 512 * 2);
  u16* Xe    = (u16*)take((size_t)6 * 768 * 1536 * 2);
  u16* h0a   = (u16*)take((size_t)768 * 1536 * 2);
  u16* h0b   = (u16*)take((size_t)768 * 1536 * 2);
  u16* h1a   = (u16*)take((size_t)768 * 1536 * 2);
  u16* h1b   = (u16*)take((size_t)768 * 1536 * 2);
  float* c0  = (float*)take((size_t)768 * 1536 * 4);
  float* c1  = (float*)take((size_t)768 * 1536 * 4);
  u16* decys = (u16*)take((size_t)6 * 768 * 1536 * 2);
  if (off > ws_size) return;   // not enough scratch: fail loudly (poison stays)

  const size_t WL = (size_t)6144 * 1536;   // per-layer weight elems
  const dim3 blk(256);

  pack_lstm_w<<<18432, blk, 0, stream>>>(eWih, Weih);
  pack_lstm_w<<<18432, blk, 0, stream>>>(eWhh, Wehh);
  pack_lstm_w<<<18432, blk, 0, stream>>>(dWih, Wdih);
  pack_lstm_w<<<18432, blk, 0, stream>>>(dWhh, Wdhh);
  pack_bias_lstm<<<48, blk, 0, stream>>>(ebih, ebhh, bcE);
  pack_bias_lstm<<<48, blk, 0, stream>>>(dbih, dbhh, bcD);
  pack_qkvT<<<4608, blk, 0, stream>>>(Wq, Wk, Wv, Wqkv);
  pack_bias<<<6, blk, 0, stream>>>(bq, bk, bv, bqkv);
  pack_WoT<<<1536, blk, 0, stream>>>(Wo, WoT);
  build_Xe<<<6912, blk, 0, stream>>>(x, Xe);

  hipMemsetAsync(h0a, 0, (size_t)768 * 1536 * 2, stream);
  hipMemsetAsync(h1a, 0, (size_t)768 * 1536 * 2, stream);
  hipMemsetAsync(c0, 0, (size_t)768 * 1536 * 4, stream);
  hipMemsetAsync(c1, 0, (size_t)768 * 1536 * 4, stream);

  u16* h0[2] = {h0a, h0b};
  u16* h1[2] = {h1a, h1b};
  int p = 0;
  // ---- encoder: 6 steps, 2 layers (fused cells) ----
  for (int s = 0; s < 6; ++s) {
    lstm_cell2<<<256, blk, 0, stream>>>(Xe + (size_t)s * 768 * 1536, h0[p],
                                        Weih, Wehh, bcE, c0, h0[p ^ 1], nullptr);
    lstm_cell2<<<256, blk, 0, stream>>>(h0[p ^ 1], h1[p],
                                        Weih + WL, Wehh + WL, bcE + 6144,
                                        c1, h1[p ^ 1], nullptr);
    p ^= 1;
  }
  // ---- decoder: 6 autoregressive steps ----
  for (int t = 0; t < 6; ++t) {
    lstm_cell2<<<256, blk, 0, stream>>>(h1[p], h0[p],
                                        Wdih, Wdhh, bcD, c0, h0[p ^ 1], nullptr);
    lstm_cell2<<<256, blk, 0, stream>>>(h0[p ^ 1], h1[p],
                                        Wdih + WL, Wdhh + WL, bcD + 6144,
                                        c1, h1[p ^ 1], decys + (size_t)t * 768 * 1536);
    p ^= 1;
  }
  // ---- attention (weight region now dead; aliases become live) ----
  build_xt<<<6912, blk, 0, stream>>>(decys, xtb);
  gemm_bt<1, 1><<<dim3(12, 72), blk, 0, stream>>>(xtb, Wqkv, 768, bqkv, Pqkv, 1536);
  attn_kernel<<<768, blk, 0, stream>>>(Pqkv, Obuf);
  gemm_bt<0, 1><<<dim3(6, 72), blk, 0, stream>>>(Obuf, WoT, 512, bo, feato, 768);
  // ---- layernorm + outputs ----
  layernorm_kernel<<<9216, blk, 0, stream>>>(feato, lng, lnb, (float*)d_out);
}

// Round 7
// 1321.250 us; speedup vs baseline: 3.0766x; 3.0766x over previous
//
#include <hip/hip_runtime.h>

// ---------------------------------------------------------------------------
// LSTM_small2 R7: R4 fused cell + counted-vmcnt 4-deep staging ring.
// lstm_cell: dual B^T GEMM (x@Wih^T + h@Whh^T) + fused gates, 128 rows x 32
// hidden cols, BK=32, 96 K-steps. Ring of 4 LDS buffers (64KB), raw s_barrier
// + s_waitcnt vmcnt(12) keeps ~12-16 loads/thread in flight (no vmcnt(0)
// drain per step — that drain was the R3-R6 bottleneck).
// ---------------------------------------------------------------------------

typedef unsigned short u16;
typedef unsigned int   u32;
typedef __bf16 bf16x8 __attribute__((ext_vector_type(8)));
typedef short  short8 __attribute__((ext_vector_type(8)));
typedef float  f32x4  __attribute__((ext_vector_type(4)));

__device__ __forceinline__ u16 f2bf(float f) {
  u32 u = __float_as_uint(f);
  u32 r = u + 0x7FFFu + ((u >> 16) & 1u);   // RNE
  return (u16)(r >> 16);
}

__device__ __forceinline__ f32x4 mfma16(short8 a, short8 b, f32x4 c) {
  return __builtin_amdgcn_mfma_f32_16x16x32_bf16(
      __builtin_bit_cast(bf16x8, a), __builtin_bit_cast(bf16x8, b), c, 0, 0, 0);
}

__device__ __forceinline__ void gload16(const u16* g, u16* l) {
  __builtin_amdgcn_global_load_lds(
      (const __attribute__((address_space(1))) u32*)g,
      (__attribute__((address_space(3))) u32*)l, 16, 0, 0);
}

// ---------------------------------------------------------------------------
// Fused LSTM cell. X,H (768x1536) bf16, Wih/Whh (6144x1536) bf16 row-major,
// biases fp32, c fp32 state, hout/h2 bf16. hout != H (ping-pong).
// Block (bm,strip): rows bm*128..+128, hidden cols strip*32..+32.
// Wave: rh=wave&1 row-half, hh=wave>>1 hidden-half; 4 n-frags = 4 gates.
// ---------------------------------------------------------------------------
__global__ __launch_bounds__(256, 2) void lstm_cell(
    const u16* __restrict__ X, const u16* __restrict__ H,
    const u16* __restrict__ Wih, const u16* __restrict__ Whh,
    const float* __restrict__ bi, const float* __restrict__ bh,
    float* __restrict__ c, u16* __restrict__ hout, u16* __restrict__ h2)
{
  __shared__ __align__(16) u16 smem[32768];   // A ring[4][4096] | B ring[4][4096]
  const int tid  = threadIdx.x;
  // XCD-chunked remap: 288 = 8 * 36, strip-major within XCD.
  const int wid  = (blockIdx.x & 7) * 36 + (blockIdx.x >> 3);
  const int strip = wid / 6;                  // [0,48): 32 hidden cols
  const int bm    = wid - strip * 6;          // [0,6): 128 rows
  const int strip32 = strip * 32;
  const int lane = tid & 63, wave = tid >> 6;
  const int rh = wave & 1, hh = wave >> 1;
  const int r16  = lane & 15, kg = lane >> 4;
  const int srow = lane >> 2, sslot = lane & 3;

  f32x4 acc[4][4];
#pragma unroll
  for (int i = 0; i < 4; ++i)
#pragma unroll
    for (int j = 0; j < 4; ++j) acc[i][j] = (f32x4)0.0f;

  // stage K-step i (0-47: X/Wih, 48-95: H/Whh) into ring buffer buf.
  // 4 gload16 per thread (2 A + 2 B).
  auto stage = [&](int i, int buf) {
    const u16* A = (i < 48) ? X : H;
    const u16* W = (i < 48) ? Wih : Whh;
    const int k0 = ((i < 48) ? i : (i - 48)) << 5;
#pragma unroll
    for (int cc2 = 0; cc2 < 2; ++cc2) {
      const int call = wave * 2 + cc2;             // 8 calls cover 128 rows
      const int row  = call * 16 + srow;
      const int slog = sslot ^ ((row >> 1) & 3);   // inverse-swizzled source
      gload16(A + (size_t)(bm * 128 + row) * 1536 + k0 + slog * 8,
              smem + buf * 4096 + call * 512);
      const int g  = call >> 1;                    // gate
      const int hr = (call & 1) * 16 + srow;       // hidden row within strip
      gload16(W + ((size_t)g * 1536 + strip32 + hr) * 1536 + k0 + slog * 8,
              smem + 16384 + buf * 4096 + call * 512);
    }
  };

  auto computeFrom = [&](int i) {
    const u16* baseA = smem + (i & 3) * 4096;
    const u16* baseB = smem + 16384 + (i & 3) * 4096;
    short8 af[4], bfr[4];
#pragma unroll
    for (int mi = 0; mi < 4; ++mi) {
      const int row = rh * 64 + mi * 16 + r16;
      af[mi] = *(const short8*)(baseA + row * 32 + ((kg ^ ((row >> 1) & 3)) << 3));
    }
#pragma unroll
    for (int ni = 0; ni < 4; ++ni) {
      const int row = ni * 32 + hh * 16 + r16;     // gate ni, hidden half hh
      bfr[ni] = *(const short8*)(baseB + row * 32 + ((kg ^ ((row >> 1) & 3)) << 3));
    }
#pragma unroll
    for (int mi = 0; mi < 4; ++mi)
#pragma unroll
      for (int ni = 0; ni < 4; ++ni)
        acc[mi][ni] = mfma16(af[mi], bfr[ni], acc[mi][ni]);
  };

  // prologue: fill the ring (16 loads/thread outstanding)
  stage(0, 0); stage(1, 1); stage(2, 2); stage(3, 3);

  for (int i = 0; i < 93; ++i) {
    asm volatile("s_waitcnt vmcnt(12)" ::: "memory");   // stage i complete
    __builtin_amdgcn_sched_barrier(0);
    __builtin_amdgcn_s_barrier();                       // all waves' stage i done
    computeFrom(i);
    __builtin_amdgcn_s_barrier();                       // all waves done reading
    __builtin_amdgcn_sched_barrier(0);
    if (i + 4 < 96) stage(i + 4, i & 3);                // overwrite oldest
  }
  asm volatile("s_waitcnt vmcnt(8)" ::: "memory");
  __builtin_amdgcn_s_barrier();
  computeFrom(93);
  __builtin_amdgcn_s_barrier();
  asm volatile("s_waitcnt vmcnt(4)" ::: "memory");
  __builtin_amdgcn_s_barrier();
  computeFrom(94);
  __builtin_amdgcn_s_barrier();
  asm volatile("s_waitcnt vmcnt(0)" ::: "memory");
  __builtin_amdgcn_s_barrier();
  computeFrom(95);

  // ---- fused gate epilogue ----
  const int h = strip32 + hh * 16 + r16;
  float bsum[4];
#pragma unroll
  for (int ni = 0; ni < 4; ++ni)
    bsum[ni] = bi[ni * 1536 + h] + bh[ni * 1536 + h];
#pragma unroll
  for (int mi = 0; mi < 4; ++mi) {
    const int row0 = bm * 128 + rh * 64 + mi * 16 + kg * 4;
#pragma unroll
    for (int j = 0; j < 4; ++j) {
      const float ig = acc[mi][0][j] + bsum[0];
      const float fg = acc[mi][1][j] + bsum[1];
      const float gz = acc[mi][2][j] + bsum[2];
      const float og = acc[mi][3][j] + bsum[3];
      const float si = 1.0f / (1.0f + expf(-ig));
      const float sf = 1.0f / (1.0f + expf(-fg));
      const float so = 1.0f / (1.0f + expf(-og));
      const size_t cij = (size_t)(row0 + j) * 1536 + h;
      const float cnew = sf * c[cij] + si * tanhf(gz);
      c[cij] = cnew;
      const u16 hv = f2bf(so * tanhf(cnew));
      hout[cij] = hv;
      if (h2) h2[cij] = hv;
    }
  }
}

// ---------------------------------------------------------------------------
// B^T GEMM (attention projections): C = A1·B1^T (+bias). 128x128 tile, BK=32.
// ---------------------------------------------------------------------------
template <int OUT_BF16, int HAS_BIAS>
__global__ __launch_bounds__(256, 2) void gemm_bt(
    const u16* __restrict__ A1, const u16* __restrict__ B1, int K1,
    const float* __restrict__ bias, void* __restrict__ Cout, int N)
{
  __shared__ __align__(16) u16 smem[16384];
  const int tid  = threadIdx.x;
  const int bn   = blockIdx.x * 128;
  const int bm   = blockIdx.y * 128;
  const int lane = tid & 63, wave = tid >> 6;
  const int wm   = (wave >> 1) * 64, wn = (wave & 1) * 64;
  const int r16  = lane & 15, kg = lane >> 4;
  const int srow = lane >> 2, sslot = lane & 3;

  f32x4 acc[4][4];
#pragma unroll
  for (int i = 0; i < 4; ++i)
#pragma unroll
    for (int j = 0; j < 4; ++j) acc[i][j] = (f32x4)0.0f;

  const int nt = K1 >> 5;
  auto stage = [&](int i, int buf) {
    const int k0 = i << 5;
#pragma unroll
    for (int cc2 = 0; cc2 < 2; ++cc2) {
      const int call = wave * 2 + cc2;
      const int row  = call * 16 + srow;
      const int slog = sslot ^ ((row >> 1) & 3);
      gload16(A1 + (size_t)(bm + row) * K1 + k0 + slog * 8, smem + buf * 4096 + call * 512);
      gload16(B1 + (size_t)(bn + row) * K1 + k0 + slog * 8, smem + 8192 + buf * 4096 + call * 512);
    }
  };

  stage(0, 0);
  __syncthreads();
  int cur = 0;
  for (int i = 0; i < nt; ++i) {
    if (i + 1 < nt) stage(i + 1, cur ^ 1);
    const u16* baseA = smem + cur * 4096;
    const u16* baseB = smem + 8192 + cur * 4096;
    short8 af[4], bfr[4];
#pragma unroll
    for (int mi = 0; mi < 4; ++mi) {
      const int row = wm + mi * 16 + r16;
      af[mi] = *(const short8*)(baseA + row * 32 + ((kg ^ ((row >> 1) & 3)) << 3));
    }
#pragma unroll
    for (int ni = 0; ni < 4; ++ni) {
      const int row = wn + ni * 16 + r16;
      bfr[ni] = *(const short8*)(baseB + row * 32 + ((kg ^ ((row >> 1) & 3)) << 3));
    }
#pragma unroll
    for (int mi = 0; mi < 4; ++mi)
#pragma unroll
      for (int ni = 0; ni < 4; ++ni)
        acc[mi][ni] = mfma16(af[mi], bfr[ni], acc[mi][ni]);
    __syncthreads();
    cur ^= 1;
  }

  const size_t Ns = (size_t)N;
#pragma unroll
  for (int ni = 0; ni < 4; ++ni) {
    const int col = bn + wn + ni * 16 + r16;
    const float bvv = HAS_BIAS ? bias[col] : 0.0f;
#pragma unroll
    for (int mi = 0; mi < 4; ++mi) {
      const int row0 = bm + wm + mi * 16 + kg * 4;
      f32x4 v = acc[mi][ni];
#pragma unroll
      for (int j = 0; j < 4; ++j) {
        const float val = v[j] + bvv;
        const size_t idx = (size_t)(row0 + j) * Ns + col;
        if (OUT_BF16) ((u16*)Cout)[idx] = f2bf(val);
        else          ((float*)Cout)[idx] = val;
      }
    }
  }
}

// ---------------------------------------------------------------------------
// Attention: one block per (nb, b); wave = head. T=12 padded to 16, DK=128.
// ---------------------------------------------------------------------------
__global__ __launch_bounds__(256) void attn_kernel(const u16* __restrict__ P, u16* __restrict__ O)
{
  __shared__ __align__(16) u16 sQ[12 * 520];
  __shared__ __align__(16) u16 sK[12 * 520];
  __shared__ __align__(16) u16 sVT[512 * 24];
  __shared__ __align__(16) u16 sS[4 * 16 * 16];
  const int tid = threadIdx.x;
  const int nb = blockIdx.x >> 8;
  const int b  = blockIdx.x & 255;
  const int qb = (nb == 1) ? 0 : 1;   // q perm [1,0,1]
  const int kb = (nb == 2) ? 0 : 2;   // k perm [2,2,0]
  const size_t rq = ((size_t)qb * 256 + b) * 12;
  const size_t rk = ((size_t)kb * 256 + b) * 12;
  const size_t rv = ((size_t)nb * 256 + b) * 12;

  for (int e4 = tid; e4 < 1536; e4 += 256) {
    const int t  = e4 >> 7;
    const int cc = (e4 & 127) * 4;
    uint2 qv = *(const uint2*)(P + (rq + t) * 1536 + cc);
    *(uint2*)(sQ + t * 520 + cc) = qv;
    uint2 kv = *(const uint2*)(P + (rk + t) * 1536 + 512 + cc);
    *(uint2*)(sK + t * 520 + cc) = kv;
    uint2 vv = *(const uint2*)(P + (rv + t) * 1536 + 1024 + cc);
    sVT[(cc + 0) * 24 + t] = (u16)(vv.x & 0xffff);
    sVT[(cc + 1) * 24 + t] = (u16)(vv.x >> 16);
    sVT[(cc + 2) * 24 + t] = (u16)(vv.y & 0xffff);
    sVT[(cc + 3) * 24 + t] = (u16)(vv.y >> 16);
  }
  for (int i = tid; i < 2048; i += 256) sVT[(i >> 2) * 24 + 12 + (i & 3)] = 0;
  __syncthreads();

  const int lane = tid & 63, h = tid >> 6;
  const int r16 = lane & 15, kg = lane >> 4;
  const int hcol = h * 128;

  f32x4 sc = (f32x4)0.0f;
#pragma unroll
  for (int ks = 0; ks < 4; ++ks) {
    short8 aq  = (r16 < 12) ? *(const short8*)(sQ + r16 * 520 + hcol + ks * 32 + kg * 8) : (short8)0;
    short8 bk2 = (r16 < 12) ? *(const short8*)(sK + r16 * 520 + hcol + ks * 32 + kg * 8) : (short8)0;
    sc = mfma16(aq, bk2, sc);   // scores[q=(kg*4+j)][tok=r16]
  }
  const float scale = 0.08838834764831845f;  // 1/sqrt(128)
#pragma unroll
  for (int j = 0; j < 4; ++j) {
    float v = (r16 < 12) ? sc[j] * scale : -1e30f;
    float m = v;
#pragma unroll
    for (int d = 1; d < 16; d <<= 1) m = fmaxf(m, __shfl_xor(m, d));
    float e = expf(v - m);
    float s = e;
#pragma unroll
    for (int d = 1; d < 16; d <<= 1) s += __shfl_xor(s, d);
    sS[h * 256 + (kg * 4 + j) * 16 + r16] = f2bf(e / s);
  }
  __syncthreads();
  short8 av = (kg < 2) ? *(const short8*)(sS + h * 256 + r16 * 16 + kg * 8) : (short8)0;
#pragma unroll
  for (int dt = 0; dt < 8; ++dt) {
    short8 bv2 = (kg < 2) ? *(const short8*)(sVT + (hcol + dt * 16 + r16) * 24 + kg * 8) : (short8)0;
    f32x4 ov = mfma16(av, bv2, (f32x4)0.0f);  // out[q=(kg*4+j)][d=dt*16+r16]
    if (kg < 3) {
#pragma unroll
      for (int j = 0; j < 4; ++j) {
        const int q = kg * 4 + j;
        O[(rv + q) * 512 + hcol + dt * 16 + r16] = f2bf(ov[j]);
      }
    }
  }
}

// ---------------------------------------------------------------------------
// LayerNorm over C=768 per row; writes feature and the [:,1:5,1:5,:] crop.
// ---------------------------------------------------------------------------
__global__ __launch_bounds__(256) void layernorm_kernel(
    const float* __restrict__ feat, const float* __restrict__ gam,
    const float* __restrict__ bet, float* __restrict__ out)
{
  const int row = blockIdx.x;
  const int b = row / 36, hidx = row - b * 36;
  const int nb = hidx / 12, t = hidx - nb * 12;
  const float* src = feat + ((size_t)nb * 3072 + b * 12 + t) * 768;
  const int tid = threadIdx.x;
  float v0 = src[tid], v1 = src[tid + 256], v2 = src[tid + 512];
  float s = v0 + v1 + v2, sq = v0 * v0 + v1 * v1 + v2 * v2;
#pragma unroll
  for (int d = 1; d < 64; d <<= 1) { s += __shfl_xor(s, d); sq += __shfl_xor(sq, d); }
  __shared__ float ps[4], pq[4];
  if ((tid & 63) == 0) { ps[tid >> 6] = s; pq[tid >> 6] = sq; }
  __syncthreads();
  s  = ps[0] + ps[1] + ps[2] + ps[3];
  sq = pq[0] + pq[1] + pq[2] + pq[3];
  const float mean = s * (1.0f / 768.0f);
  const float var  = sq * (1.0f / 768.0f) - mean * mean;
  const float rstd = rsqrtf(var + 1e-5f);
  float* dst = out + (size_t)row * 768;
  const int hh = hidx / 6, wp = hidx - hh * 6;
  float* dst2 = nullptr;
  if (hh >= 1 && hh < 5 && wp >= 1 && wp < 5)
    dst2 = out + 7077888 + ((size_t)b * 16 + (hh - 1) * 4 + (wp - 1)) * 768;
#pragma unroll
  for (int i = 0; i < 3; ++i) {
    const int cix = tid + i * 256;
    const float vv = (i == 0) ? v0 : (i == 1 ? v1 : v2);
    const float o = (vv - mean) * rstd * gam[cix] + bet[cix];
    dst[cix] = o;
    if (dst2) dst2[cix] = o;
  }
}

// --------------------------- small prep kernels ----------------------------
__global__ __launch_bounds__(256) void cast_bf16_kernel(const float* __restrict__ src,
                                                        u16* __restrict__ dst, int n4)
{
  const int i = blockIdx.x * 256 + threadIdx.x;
  if (i >= n4) return;
  float4 v = ((const float4*)src)[i];
  uint2 pk;
  pk.x = (u32)f2bf(v.x) | ((u32)f2bf(v.y) << 16);
  pk.y = (u32)f2bf(v.z) | ((u32)f2bf(v.w) << 16);
  ((uint2*)dst)[i] = pk;
}

__global__ __launch_bounds__(256) void pack_qkvT(const float* __restrict__ Wq,
    const float* __restrict__ Wk, const float* __restrict__ Wv, u16* __restrict__ dst)
{
  const int idx = blockIdx.x * 256 + threadIdx.x;   // 1536*768
  if (idx >= 1536 * 768) return;
  const int d = idx / 768, c = idx - d * 768;
  float v;
  if (d < 512)       v = Wq[(size_t)c * 512 + d];
  else if (d < 1024) v = Wk[(size_t)c * 512 + d - 512];
  else               v = Wv[(size_t)c * 512 + d - 1024];
  dst[idx] = f2bf(v);
}

__global__ __launch_bounds__(256) void pack_bias(const float* __restrict__ bq,
    const float* __restrict__ bk, const float* __restrict__ bv, float* __restrict__ dst)
{
  const int i = blockIdx.x * 256 + threadIdx.x;
  if (i < 512)       dst[i] = bq[i];
  else if (i < 1024) dst[i] = bk[i - 512];
  else if (i < 1536) dst[i] = bv[i - 1024];
}

__global__ __launch_bounds__(256) void pack_WoT(const float* __restrict__ Wo, u16* __restrict__ dst)
{
  const int idx = blockIdx.x * 256 + threadIdx.x;   // 768*512
  if (idx >= 768 * 512) return;
  const int n = idx / 512, k = idx - n * 512;
  dst[idx] = f2bf(Wo[(size_t)k * 768 + n]);
}

// Xe[s][r][k] = x[b][(nb*2+r2)*6 + (5-s)][c], r=nb*256+b, k=r2*768+c  (bf16)
__global__ __launch_bounds__(256) void build_Xe(const float* __restrict__ x, u16* __restrict__ Xe)
{
  const int i4 = blockIdx.x * 256 + threadIdx.x;   // < 1769472
  if (i4 >= 1769472) return;
  const int e = i4 * 4;
  const int c = e % 768;
  const int r2 = (e / 768) & 1;
  const int r = (e / 1536) % 768;
  const int s = e / 1179648;
  const int nb = r >> 8, bb = r & 255;
  const int w = 5 - s;
  const float* src = x + ((size_t)bb * 36 + (nb * 2 + r2) * 6 + w) * 768 + c;
  float4 v = *(const float4*)src;
  uint2 pk;
  pk.x = (u32)f2bf(v.x) | ((u32)f2bf(v.y) << 16);
  pk.y = (u32)f2bf(v.z) | ((u32)f2bf(v.w) << 16);
  ((uint2*)Xe)[i4] = pk;
}

// xt[nb][b][t][c] = dec_ys[s][nb*256+b][r2*768+c], t = r2*6+s  (bf16 copy)
__global__ __launch_bounds__(256) void build_xt(const u16* __restrict__ decys, u16* __restrict__ xt)
{
  const int i4 = blockIdx.x * 256 + threadIdx.x;   // < 1769472
  if (i4 >= 1769472) return;
  const int e = i4 * 4;
  const int c = e % 768;
  const int t = (e / 768) % 12;
  const int b = (e / 9216) % 256;
  const int nb = e / 2359296;
  const int r2 = t / 6, s = t - r2 * 6;
  const u16* src = decys + ((size_t)s * 768 + nb * 256 + b) * 1536 + r2 * 768 + c;
  ((uint2*)xt)[i4] = *(const uint2*)src;
}

// ---------------------------------------------------------------------------
extern "C" void kernel_launch(void* const* d_in, const int* in_sizes, int n_in,
                              void* d_out, int out_size, void* d_ws, size_t ws_size,
                              hipStream_t stream)
{
  const float* x    = (const float*)d_in[0];
  const float* eWih = (const float*)d_in[1];
  const float* eWhh = (const float*)d_in[2];
  const float* ebih = (const float*)d_in[3];
  const float* ebhh = (const float*)d_in[4];
  const float* dWih = (const float*)d_in[5];
  const float* dWhh = (const float*)d_in[6];
  const float* dbih = (const float*)d_in[7];
  const float* dbhh = (const float*)d_in[8];
  const float* Wq = (const float*)d_in[9];
  const float* bq = (const float*)d_in[10];
  const float* Wk = (const float*)d_in[11];
  const float* bk = (const float*)d_in[12];
  const float* Wv = (const float*)d_in[13];
  const float* bv = (const float*)d_in[14];
  const float* Wo = (const float*)d_in[15];
  const float* bo = (const float*)d_in[16];
  const float* lng = (const float*)d_in[17];
  const float* lnb = (const float*)d_in[18];

  char* ws = (char*)d_ws;
  // region0: bf16 weights (4 x 37,748,736 B), aliased post-decoder by
  // the attention-phase temporaries.
  const size_t WBYTES = 37748736;
  u16* Weih = (u16*)(ws);
  u16* Wehh = (u16*)(ws + WBYTES);
  u16* Wdih = (u16*)(ws + 2 * WBYTES);
  u16* Wdhh = (u16*)(ws + 3 * WBYTES);
  u16*   xtb   = (u16*)(ws);
  u16*   Pqkv  = (u16*)(ws + 14155776);
  u16*   Obuf  = (u16*)(ws + 14155776 + 28311552);
  float* feato = (float*)(ws + 14155776 + 28311552 + 9437184);
  size_t off = 4 * WBYTES;
  auto take = [&](size_t bytes) -> char* {
    char* p = ws + off;
    off = (off + bytes + 255) & ~(size_t)255;
    return p;
  };
  u16* Wqkv  = (u16*)take((size_t)1536 * 768 * 2);
  float* bqkv = (float*)take(1536 * 4);
  u16* WoT   = (u16*)take((size_t)768 * 512 * 2);
  u16* Xe    = (u16*)take((size_t)6 * 768 * 1536 * 2);
  u16* h0a   = (u16*)take((size_t)768 * 1536 * 2);
  u16* h0b   = (u16*)take((size_t)768 * 1536 * 2);
  u16* h1a   = (u16*)take((size_t)768 * 1536 * 2);
  u16* h1b   = (u16*)take((size_t)768 * 1536 * 2);
  float* c0  = (float*)take((size_t)768 * 1536 * 4);
  float* c1  = (float*)take((size_t)768 * 1536 * 4);
  u16* decys = (u16*)take((size_t)6 * 768 * 1536 * 2);
  if (off > ws_size) return;   // not enough scratch: fail loudly (poison stays)

  const size_t WL = (size_t)6144 * 1536;   // per-layer weight elems
  const dim3 blk(256);

  cast_bf16_kernel<<<18432, blk, 0, stream>>>(eWih, Weih, 4718592);
  cast_bf16_kernel<<<18432, blk, 0, stream>>>(eWhh, Wehh, 4718592);
  cast_bf16_kernel<<<18432, blk, 0, stream>>>(dWih, Wdih, 4718592);
  cast_bf16_kernel<<<18432, blk, 0, stream>>>(dWhh, Wdhh, 4718592);
  pack_qkvT<<<4608, blk, 0, stream>>>(Wq, Wk, Wv, Wqkv);
  pack_bias<<<6, blk, 0, stream>>>(bq, bk, bv, bqkv);
  pack_WoT<<<1536, blk, 0, stream>>>(Wo, WoT);
  build_Xe<<<6912, blk, 0, stream>>>(x, Xe);

  hipMemsetAsync(h0a, 0, (size_t)768 * 1536 * 2, stream);
  hipMemsetAsync(h1a, 0, (size_t)768 * 1536 * 2, stream);
  hipMemsetAsync(c0, 0, (size_t)768 * 1536 * 4, stream);
  hipMemsetAsync(c1, 0, (size_t)768 * 1536 * 4, stream);

  u16* h0[2] = {h0a, h0b};
  u16* h1[2] = {h1a, h1b};
  int p = 0;
  // ---- encoder: 6 steps, 2 layers (fused cells) ----
  for (int s = 0; s < 6; ++s) {
    lstm_cell<<<288, blk, 0, stream>>>(Xe + (size_t)s * 768 * 1536, h0[p],
                                       Weih, Wehh, ebih, ebhh, c0, h0[p ^ 1], nullptr);
    lstm_cell<<<288, blk, 0, stream>>>(h0[p ^ 1], h1[p],
                                       Weih + WL, Wehh + WL, ebih + 6144, ebhh + 6144,
                                       c1, h1[p ^ 1], nullptr);
    p ^= 1;
  }
  // ---- decoder: 6 autoregressive steps ----
  for (int t = 0; t < 6; ++t) {
    lstm_cell<<<288, blk, 0, stream>>>(h1[p], h0[p],
                                       Wdih, Wdhh, dbih, dbhh, c0, h0[p ^ 1], nullptr);
    lstm_cell<<<288, blk, 0, stream>>>(h0[p ^ 1], h1[p],
                                       Wdih + WL, Wdhh + WL, dbih + 6144, dbhh + 6144,
                                       c1, h1[p ^ 1], decys + (size_t)t * 768 * 1536);
    p ^= 1;
  }
  // ---- attention (weight region now dead; aliases become live) ----
  build_xt<<<6912, blk, 0, stream>>>(decys, xtb);
  gemm_bt<1, 1><<<dim3(12, 72), blk, 0, stream>>>(xtb, Wqkv, 768, bqkv, Pqkv, 1536);
  attn_kernel<<<768, blk, 0, stream>>>(Pqkv, Obuf);
  gemm_bt<0, 1><<<dim3(6, 72), blk, 0, stream>>>(Obuf, WoT, 512, bo, feato, 768);
  // ---- layernorm + outputs ----
  layernorm_kernel<<<9216, blk, 0, stream>>>(feato, lng, lnb, (float*)d_out);
}